// Round 4
// baseline (308.908 us; speedup 1.0000x reference)
//
#include <hip/hip_runtime.h>

typedef unsigned short u16;
typedef __attribute__((ext_vector_type(4))) unsigned short u16x4;
typedef __attribute__((ext_vector_type(8))) short short8;
typedef __attribute__((ext_vector_type(4))) float floatx4;

#define NB 8192        // rows
#define DK 1024        // D_IN
#define DN 1024        // D_OUT
#define NE 16          // experts
#define TM 128
#define TN 128
#define BK 64
#define MAX_TILES 80   // sum ceil(cnt_e/128) <= 64 + 16
#define GTHR 0.15f     // bf16-gate ambiguity threshold (~50 sigma)

__device__ __forceinline__ u16 f2bf(float f) {
    union { float f; unsigned int u; } v; v.f = f;
    unsigned int u = v.u;
    return (u16)((u + 0x7fffu + ((u >> 16) & 1u)) >> 16);
}

__device__ __forceinline__ void gld16(const void* g, void* l) {
    __builtin_amdgcn_global_load_lds(
        (const __attribute__((address_space(1))) unsigned int*)g,
        (__attribute__((address_space(3))) unsigned int*)l, 16, 0, 0);
}

// ---------------- K1: bf16-MFMA gate + x->bf16 + ambiguity flagging ----------------
// 256 blocks x 256 thr; 32 rows/block. Wave w owns k-slice [w*256, w*256+256).
// Per-wave-private LDS slices -> no cross-wave data sharing until final reduce.
__global__ __launch_bounds__(256) void k_gate(const float* __restrict__ x,
                                              const float* __restrict__ Wg,
                                              const float* __restrict__ bg,
                                              u16* __restrict__ xb,
                                              int* __restrict__ cnt,
                                              int* __restrict__ bucket,
                                              int* __restrict__ fixcnt,
                                              int* __restrict__ fixlist) {
    __shared__ u16 xs[4][32 * 64];      // per-wave A tile [row][k8-slot], xor-swizzled
    __shared__ u16 wgt[4][16 * 256];    // per-wave B tile [e][k8-slot], xor-swizzled
    __shared__ float gred[4][32 * 17];  // per-wave partial gate, pad 17 (conflict-free)

    const int tid = threadIdx.x;
    const int lane = tid & 63;
    const int w = tid >> 6;
    const int lr = lane & 15, q = lane >> 4;
    const int R0 = blockIdx.x * 32;
    const int kw = w * 256;             // wave k-base

    // ---- stage WgT slice bf16 swizzled: coalesced float4 reads + b16 scatter ----
    #pragma unroll
    for (int i = 0; i < 16; ++i) {
        int f = i * 64 + lane;          // float4 index over [256 k][4 quads]
        int k = f >> 2;                 // local k 0..255
        int e4 = (f & 3) * 4;
        float4 v = *(const float4*)&Wg[(size_t)(kw + k) * NE + e4];
        int s = k >> 3, j = k & 7;
        wgt[w][(e4 + 0) * 256 + (s ^ ((e4 + 0) & 7)) * 8 + j] = f2bf(v.x);
        wgt[w][(e4 + 1) * 256 + (s ^ ((e4 + 1) & 7)) * 8 + j] = f2bf(v.y);
        wgt[w][(e4 + 2) * 256 + (s ^ ((e4 + 2) & 7)) * 8 + j] = f2bf(v.z);
        wgt[w][(e4 + 3) * 256 + (s ^ ((e4 + 3) & 7)) * 8 + j] = f2bf(v.w);
    }

    floatx4 acc[2];
    acc[0] = (floatx4)0.0f; acc[1] = (floatx4)0.0f;

    for (int cc = 0; cc < 4; ++cc) {
        // stage xs [32 rows][64 k] bf16 swizzled + emit xb global copy
        #pragma unroll
        for (int i = 0; i < 4; ++i) {
            int c = i * 64 + lane;
            int r = c >> 3, s8 = c & 7;
            const float* gp = &x[(size_t)(R0 + r) * DK + kw + cc * 64 + s8 * 8];
            float4 v0 = *(const float4*)gp;
            float4 v1 = *(const float4*)(gp + 4);
            u16 pk[8] = { f2bf(v0.x), f2bf(v0.y), f2bf(v0.z), f2bf(v0.w),
                          f2bf(v1.x), f2bf(v1.y), f2bf(v1.z), f2bf(v1.w) };
            *(short8*)&xs[w][r * 64 + ((s8 ^ (r & 7)) * 8)] = *(const short8*)pk;
            *(short8*)&xb[(size_t)(R0 + r) * DK + kw + cc * 64 + s8 * 8] = *(const short8*)pk;
        }
        __syncthreads();
        #pragma unroll
        for (int kwin = 0; kwin < 2; ++kwin) {
            int sg = kwin * 4 + q;      // k8-slot within sub-chunk
            short8 bf = *(const short8*)&wgt[w][lr * 256 + ((cc * 8 + sg) ^ (lr & 7)) * 8];
            #pragma unroll
            for (int mt = 0; mt < 2; ++mt) {
                int row = mt * 16 + lr;
                short8 af = *(const short8*)&xs[w][row * 64 + ((sg ^ (row & 7)) * 8)];
                acc[mt] = __builtin_amdgcn_mfma_f32_16x16x32_bf16(af, bf, acc[mt], 0, 0, 0);
            }
        }
        __syncthreads();
    }

    // write per-wave partials (C/D layout: col=lane&15, row=q*4+reg)
    #pragma unroll
    for (int mt = 0; mt < 2; ++mt)
        #pragma unroll
        for (int rr = 0; rr < 4; ++rr)
            gred[w][(mt * 16 + q * 4 + rr) * 17 + lr] = acc[mt][rr];
    __syncthreads();

    if (tid < 32) {
        int row = R0 + tid;
        float g[16];
        #pragma unroll
        for (int e = 0; e < 16; ++e)
            g[e] = gred[0][tid * 17 + e] + gred[1][tid * 17 + e]
                 + gred[2][tid * 17 + e] + gred[3][tid * 17 + e] + bg[e];
        float best = g[0], second = -1e30f; int bi = 0;
        #pragma unroll
        for (int e = 1; e < 16; ++e) {
            if (g[e] > best) { second = best; best = g[e]; bi = e; }
            else if (g[e] > second) second = g[e];
        }
        if (best - second >= GTHR) {
            int pos = atomicAdd(&cnt[bi], 1);
            bucket[bi * NB + pos] = row;
        } else {
            int f = atomicAdd(fixcnt, 1);
            fixlist[f] = row;
        }
    }
}

// ---------------- K1b: fp64 exact re-gate of ambiguous rows ----------------
// wave per row; lane k-split; butterfly reduce per expert.
__global__ __launch_bounds__(256) void k_fix(const float* __restrict__ x,
                                             const float* __restrict__ Wg,
                                             const float* __restrict__ bg,
                                             const int* __restrict__ fixcnt,
                                             const int* __restrict__ fixlist,
                                             int* __restrict__ cnt,
                                             int* __restrict__ bucket) {
    const int lane = threadIdx.x & 63;
    const int wid = blockIdx.x * 4 + (threadIdx.x >> 6);
    const int n = *fixcnt;
    for (int idx = wid; idx < n; idx += 256) {
        int row = fixlist[idx];
        float4 xv[4];
        #pragma unroll
        for (int i = 0; i < 4; ++i)
            xv[i] = *(const float4*)&x[(size_t)row * DK + i * 256 + lane * 4];
        double acc[16];
        #pragma unroll
        for (int e = 0; e < 16; ++e) acc[e] = 0.0;
        #pragma unroll
        for (int i = 0; i < 4; ++i) {
            const float* xf = (const float*)&xv[i];
            #pragma unroll
            for (int j = 0; j < 4; ++j) {
                int k = i * 256 + lane * 4 + j;
                double xd = (double)xf[j];
                const float4* wr = (const float4*)&Wg[(size_t)k * NE];
                float4 w0 = wr[0], w1 = wr[1], w2 = wr[2], w3 = wr[3];
                acc[0]  += xd * (double)w0.x;  acc[1]  += xd * (double)w0.y;
                acc[2]  += xd * (double)w0.z;  acc[3]  += xd * (double)w0.w;
                acc[4]  += xd * (double)w1.x;  acc[5]  += xd * (double)w1.y;
                acc[6]  += xd * (double)w1.z;  acc[7]  += xd * (double)w1.w;
                acc[8]  += xd * (double)w2.x;  acc[9]  += xd * (double)w2.y;
                acc[10] += xd * (double)w2.z;  acc[11] += xd * (double)w2.w;
                acc[12] += xd * (double)w3.x;  acc[13] += xd * (double)w3.y;
                acc[14] += xd * (double)w3.z;  acc[15] += xd * (double)w3.w;
            }
        }
        #pragma unroll
        for (int e = 0; e < 16; ++e) {
            double v = acc[e];
            #pragma unroll
            for (int off = 1; off < 64; off <<= 1)
                v += __shfl_xor(v, off);
            acc[e] = v + (double)bg[e];
        }
        if (lane == 0) {
            double best = acc[0]; int bi = 0;
            #pragma unroll
            for (int e = 1; e < 16; ++e)
                if (acc[e] > best) { best = acc[e]; bi = e; }
            int pos = atomicAdd(&cnt[bi], 1);
            bucket[bi * NB + pos] = row;
        }
    }
}

// ---------------- K2: We fp32 [E][K][N] -> bf16 transposed [E][N][K] ----------------
__global__ __launch_bounds__(256) void k_wet(const float* __restrict__ We,
                                             u16* __restrict__ WeT) {
    __shared__ float t[64 * 65];
    const int bw = blockIdx.x;
    const int e  = bw >> 8;
    const int n0 = ((bw >> 4) & 15) * 64;
    const int k0 = (bw & 15) * 64;
    const int tid = threadIdx.x;
    const float* src = We + (size_t)e * DK * DN;

    const int n4 = (tid & 15) * 4;
    const int kl = tid >> 4;
    #pragma unroll
    for (int r = 0; r < 4; ++r) {
        int k = r * 16 + kl;
        float4 v = *(const float4*)&src[(size_t)(k0 + k) * DN + n0 + n4];
        t[k * 65 + n4 + 0] = v.x;
        t[k * 65 + n4 + 1] = v.y;
        t[k * 65 + n4 + 2] = v.z;
        t[k * 65 + n4 + 3] = v.w;
    }
    __syncthreads();
    u16* dst = WeT + (size_t)e * DN * DK;
    #pragma unroll
    for (int r = 0; r < 2; ++r) {
        int idx = r * 256 + tid;
        int nl = idx >> 3;
        int k8 = idx & 7;
        u16 pk[8];
        #pragma unroll
        for (int i = 0; i < 8; ++i)
            pk[i] = f2bf(t[(k8 * 8 + i) * 65 + nl]);
        *(short8*)&dst[(size_t)(n0 + nl) * DK + k0 + k8 * 8] = *(const short8*)pk;
    }
}

// ---------------- K3: grouped GEMM, bf16 MFMA 16x16x32, 128x128 tile ----------------
__global__ __launch_bounds__(256) void k_moe(const u16* __restrict__ xb,
                                             const u16* __restrict__ WeT,
                                             const float* __restrict__ be,
                                             const int* __restrict__ bucket,
                                             const int* __restrict__ cnt,
                                             float* __restrict__ out) {
    const int slot = blockIdx.x >> 3;
    const int nt = blockIdx.x & 7;

    int e = -1, mt = 0, cntE = 0, acc_t = 0;
    #pragma unroll
    for (int ee = 0; ee < NE; ++ee) {
        int ce = cnt[ee];
        int nte = (ce + TM - 1) / TM;
        if (e < 0 && slot < acc_t + nte) { e = ee; mt = slot - acc_t; cntE = ce; }
        acc_t += nte;
    }
    if (e < 0) return;

    const int m0 = mt * TM;
    const int n0 = nt * TN;

    __shared__ u16 aLds[TM * BK];
    __shared__ u16 bLds[TN * BK];

    const int tid = threadIdx.x;
    const int lane = tid & 63;
    const int w = tid >> 6;
    const int wr = w >> 1, wc = w & 1;
    const int lr = lane & 15, q = lane >> 4;

    long aoff[4]; long boff[4]; int ldsb[4];
    #pragma unroll
    for (int r = 0; r < 4; ++r) {
        int c = r * 256 + tid;
        int row = c >> 3;
        int k8 = (c & 7) ^ (row & 7);
        int m_idx = m0 + row; if (m_idx >= cntE) m_idx = cntE - 1;
        long rid = bucket[e * NB + m_idx];
        aoff[r] = rid * DK + k8 * 8;
        boff[r] = (long)e * DN * DK + (long)(n0 + row) * DK + k8 * 8;
        ldsb[r] = (r * 256 + (tid & ~63)) * 8;
    }

    floatx4 acc[4][4];
    #pragma unroll
    for (int mi = 0; mi < 4; ++mi)
        #pragma unroll
        for (int ni = 0; ni < 4; ++ni)
            acc[mi][ni] = (floatx4)0.0f;

    for (int kk = 0; kk < DK; kk += BK) {
        #pragma unroll
        for (int r = 0; r < 4; ++r) {
            gld16(xb + aoff[r] + kk, &aLds[ldsb[r]]);
            gld16(WeT + boff[r] + kk, &bLds[ldsb[r]]);
        }
        __syncthreads();
        #pragma unroll
        for (int ks = 0; ks < 2; ++ks) {
            short8 af[4], bfr[4];
            const int slot_k = ((ks << 2) + q) ^ (lr & 7);
            #pragma unroll
            for (int mi = 0; mi < 4; ++mi) {
                int row = wr * 64 + mi * 16 + lr;
                af[mi] = *(const short8*)&aLds[row * BK + slot_k * 8];
                int nrow = wc * 64 + mi * 16 + lr;
                bfr[mi] = *(const short8*)&bLds[nrow * BK + slot_k * 8];
            }
            #pragma unroll
            for (int mi = 0; mi < 4; ++mi)
                #pragma unroll
                for (int ni = 0; ni < 4; ++ni)
                    acc[mi][ni] = __builtin_amdgcn_mfma_f32_16x16x32_bf16(
                        af[mi], bfr[ni], acc[mi][ni], 0, 0, 0);
        }
        __syncthreads();
    }

    float bias[4];
    #pragma unroll
    for (int ni = 0; ni < 4; ++ni)
        bias[ni] = be[e * DN + n0 + wc * 64 + ni * 16 + lr];

    #pragma unroll
    for (int mi = 0; mi < 4; ++mi) {
        #pragma unroll
        for (int rr = 0; rr < 4; ++rr) {
            int row_l = wr * 64 + mi * 16 + q * 4 + rr;
            int m_idx = m0 + row_l;
            if (m_idx < cntE) {
                long rid = bucket[e * NB + m_idx];
                float* orow = out + rid * DN + n0 + wc * 64 + lr;
                #pragma unroll
                for (int ni = 0; ni < 4; ++ni)
                    orow[ni * 16] = acc[mi][ni][rr] + bias[ni];
            }
        }
    }
}

extern "C" void kernel_launch(void* const* d_in, const int* in_sizes, int n_in,
                              void* d_out, int out_size, void* d_ws, size_t ws_size,
                              hipStream_t stream) {
    const float* x  = (const float*)d_in[0];
    const float* Wg = (const float*)d_in[1];
    const float* bg = (const float*)d_in[2];
    const float* We = (const float*)d_in[3];
    const float* be = (const float*)d_in[4];
    float* out = (float*)d_out;

    int* cnt     = (int*)d_ws;          // 16 ints
    int* fixcnt  = cnt + 16;            // 1 int
    int* fixlist = cnt + 32;            // up to 8192 ints
    int* bucket  = cnt + 8448;          // 16*8192 ints (ends < 1 MB)
    u16* xb  = (u16*)((char*)d_ws + (1u << 20));    // 16 MB @ 1MB
    u16* wet = (u16*)((char*)d_ws + (18u << 20));   // 32 MB @ 18MB

    hipMemsetAsync(cnt, 0, 20 * sizeof(int), stream);
    k_gate<<<256, 256, 0, stream>>>(x, Wg, bg, xb, cnt, bucket, fixcnt, fixlist);
    k_fix<<<64, 256, 0, stream>>>(x, Wg, bg, fixcnt, fixlist, cnt, bucket);
    k_wet<<<4096, 256, 0, stream>>>(We, wet);
    k_moe<<<MAX_TILES * 8, 256, 0, stream>>>(xb, wet, be, bucket, cnt, out);
}

// Round 5
// 232.683 us; speedup vs baseline: 1.3276x; 1.3276x over previous
//
#include <hip/hip_runtime.h>

typedef unsigned short u16;
typedef __attribute__((ext_vector_type(4))) unsigned short u16x4;
typedef __attribute__((ext_vector_type(8))) short short8;
typedef __attribute__((ext_vector_type(4))) float floatx4;

#define NB 8192        // rows
#define DK 1024        // D_IN
#define DN 1024        // D_OUT
#define NE 16          // experts
#define TM 128
#define TN 128
#define BK 64
#define MAX_TILES 80   // sum ceil(cnt_e/128) <= 64 + 16
#define GTHR 4e-3f     // split-bf16 gate error < 1e-4 worst-case; 40x margin

__device__ __forceinline__ u16 f2bf(float f) {
    union { float f; unsigned int u; } v; v.f = f;
    unsigned int u = v.u;
    return (u16)((u + 0x7fffu + ((u >> 16) & 1u)) >> 16);
}

__device__ __forceinline__ float bf2f(u16 h) {
    union { unsigned int u; float f; } v; v.u = ((unsigned int)h) << 16;
    return v.f;
}

__device__ __forceinline__ void gld16(const void* g, void* l) {
    __builtin_amdgcn_global_load_lds(
        (const __attribute__((address_space(1))) unsigned int*)g,
        (__attribute__((address_space(3))) unsigned int*)l, 16, 0, 0);
}

// ---------------- K1: split-bf16 MFMA gate + x->bf16 + ambiguity flagging ----------------
// 512 blocks x 256 thr; 16 rows/block. Wave w owns k-slice [w*256, (w+1)*256).
// gate = MFMA(x_hi,w_hi) + MFMA(x_hi,w_lo) + MFMA(x_lo,w_hi)  (error ~1e-5)
__global__ __launch_bounds__(256) void k_gate(const float* __restrict__ x,
                                              const float* __restrict__ Wg,
                                              const float* __restrict__ bg,
                                              u16* __restrict__ xb,
                                              int* __restrict__ cnt,
                                              int* __restrict__ bucket,
                                              int* __restrict__ fixcnt,
                                              int* __restrict__ fixlist) {
    __shared__ u16 xsh[4][16 * 64];     // per-wave A-hi tile, xor-swizzled k8 slots
    __shared__ u16 xsl[4][16 * 64];     // A-lo
    __shared__ u16 wgh[4][16 * 64];     // per-wave B-hi tile [e][k8], per-chunk
    __shared__ u16 wgl[4][16 * 64];     // B-lo
    __shared__ float gred[4][16 * 17];  // per-wave partial gate, pad 17

    const int tid = threadIdx.x;
    const int lane = tid & 63;
    const int w = tid >> 6;
    const int lr = lane & 15, q = lane >> 4;
    const int R0 = blockIdx.x * 16;
    const int kw = w * 256;             // wave k-base

    floatx4 acc = (floatx4)0.0f;

    for (int cc = 0; cc < 4; ++cc) {
        const int kc = kw + cc * 64;
        // ---- stage x rows: hi+lo bf16 swizzled + emit xb (hi) global copy ----
        #pragma unroll
        for (int i = 0; i < 2; ++i) {
            int c = i * 64 + lane;      // 0..127 over [16 rows][8 slots]
            int r = c >> 3, s8 = c & 7;
            const float* gp = &x[(size_t)(R0 + r) * DK + kc + s8 * 8];
            float4 v0 = *(const float4*)gp;
            float4 v1 = *(const float4*)(gp + 4);
            float vv[8] = { v0.x, v0.y, v0.z, v0.w, v1.x, v1.y, v1.z, v1.w };
            u16 hi[8], lo[8];
            #pragma unroll
            for (int j = 0; j < 8; ++j) {
                hi[j] = f2bf(vv[j]);
                lo[j] = f2bf(vv[j] - bf2f(hi[j]));
            }
            int a = r * 64 + ((s8 ^ (r & 7)) * 8);
            *(short8*)&xsh[w][a] = *(const short8*)hi;
            *(short8*)&xsl[w][a] = *(const short8*)lo;
            *(short8*)&xb[(size_t)(R0 + r) * DK + kc + s8 * 8] = *(const short8*)hi;
        }
        // ---- stage Wg chunk transposed hi+lo: [64 k][16 e] -> [e][k8 swizzled] ----
        #pragma unroll
        for (int i = 0; i < 4; ++i) {
            int f = i * 64 + lane;      // 0..255 float4 index over [64 k][4 e-quads]
            int k = f >> 2;             // 0..63
            int e4 = (f & 3) * 4;
            float4 v = *(const float4*)&Wg[(size_t)(kc + k) * NE + e4];
            int s = k >> 3, j = k & 7;
            float vv[4] = { v.x, v.y, v.z, v.w };
            #pragma unroll
            for (int t = 0; t < 4; ++t) {
                int er = e4 + t;
                u16 hi = f2bf(vv[t]);
                u16 lo = f2bf(vv[t] - bf2f(hi));
                int a = er * 64 + ((s ^ (er & 7)) * 8 + j);
                wgh[w][a] = hi;
                wgl[w][a] = lo;
            }
        }
        __syncthreads();
        #pragma unroll
        for (int kwin = 0; kwin < 2; ++kwin) {
            int sg = kwin * 4 + q;
            int ab = lr * 64 + ((sg ^ (lr & 7)) * 8);
            short8 bh = *(const short8*)&wgh[w][ab];
            short8 bl = *(const short8*)&wgl[w][ab];
            short8 ah = *(const short8*)&xsh[w][ab];
            short8 al = *(const short8*)&xsl[w][ab];
            acc = __builtin_amdgcn_mfma_f32_16x16x32_bf16(ah, bh, acc, 0, 0, 0);
            acc = __builtin_amdgcn_mfma_f32_16x16x32_bf16(ah, bl, acc, 0, 0, 0);
            acc = __builtin_amdgcn_mfma_f32_16x16x32_bf16(al, bh, acc, 0, 0, 0);
        }
        __syncthreads();
    }

    // per-wave partials (C/D: col=lane&15 (expert), row=q*4+reg (local row))
    #pragma unroll
    for (int rr = 0; rr < 4; ++rr)
        gred[w][(q * 4 + rr) * 17 + lr] = acc[rr];
    __syncthreads();

    if (tid < 16) {
        int row = R0 + tid;
        float g[16];
        #pragma unroll
        for (int e = 0; e < 16; ++e)
            g[e] = gred[0][tid * 17 + e] + gred[1][tid * 17 + e]
                 + gred[2][tid * 17 + e] + gred[3][tid * 17 + e] + bg[e];
        float best = g[0], second = -1e30f; int bi = 0;
        #pragma unroll
        for (int e = 1; e < 16; ++e) {
            if (g[e] > best) { second = best; best = g[e]; bi = e; }
            else if (g[e] > second) second = g[e];
        }
        if (best - second >= GTHR) {
            int pos = atomicAdd(&cnt[bi], 1);
            bucket[bi * NB + pos] = row;
        } else {
            int f = atomicAdd(fixcnt, 1);
            fixlist[f] = row;
        }
    }
}

// ---------------- K1b: fp64 exact re-gate of ambiguous rows ----------------
// one block (256 thr) per row: thread k-split (4 k each), wave butterfly + LDS reduce.
__global__ __launch_bounds__(256) void k_fix(const float* __restrict__ x,
                                             const float* __restrict__ Wg,
                                             const float* __restrict__ bg,
                                             const int* __restrict__ fixcnt,
                                             const int* __restrict__ fixlist,
                                             int* __restrict__ cnt,
                                             int* __restrict__ bucket) {
    __shared__ double lred[4][16];
    const int tid = threadIdx.x;
    const int lane = tid & 63;
    const int w = tid >> 6;
    const int n = *fixcnt;
    for (int it = blockIdx.x; it < n; it += 256) {
        const int row = fixlist[it];
        float4 xv = *(const float4*)&x[(size_t)row * DK + tid * 4];
        const float* xf = (const float*)&xv;
        double acc[16];
        #pragma unroll
        for (int e = 0; e < 16; ++e) acc[e] = 0.0;
        #pragma unroll
        for (int j = 0; j < 4; ++j) {
            int k = tid * 4 + j;
            double xd = (double)xf[j];
            const float4* wr = (const float4*)&Wg[(size_t)k * NE];
            float4 w0 = wr[0], w1 = wr[1], w2 = wr[2], w3 = wr[3];
            acc[0]  += xd * (double)w0.x;  acc[1]  += xd * (double)w0.y;
            acc[2]  += xd * (double)w0.z;  acc[3]  += xd * (double)w0.w;
            acc[4]  += xd * (double)w1.x;  acc[5]  += xd * (double)w1.y;
            acc[6]  += xd * (double)w1.z;  acc[7]  += xd * (double)w1.w;
            acc[8]  += xd * (double)w2.x;  acc[9]  += xd * (double)w2.y;
            acc[10] += xd * (double)w2.z;  acc[11] += xd * (double)w2.w;
            acc[12] += xd * (double)w3.x;  acc[13] += xd * (double)w3.y;
            acc[14] += xd * (double)w3.z;  acc[15] += xd * (double)w3.w;
        }
        #pragma unroll
        for (int e = 0; e < 16; ++e) {
            double v = acc[e];
            #pragma unroll
            for (int off = 1; off < 64; off <<= 1)
                v += __shfl_xor(v, off);
            acc[e] = v;
        }
        if (lane == 0) {
            #pragma unroll
            for (int e = 0; e < 16; ++e) lred[w][e] = acc[e];
        }
        __syncthreads();
        if (tid == 0) {
            double best = -1e300; int bi = 0;
            #pragma unroll
            for (int e = 0; e < 16; ++e) {
                double g = lred[0][e] + lred[1][e] + lred[2][e] + lred[3][e]
                         + (double)bg[e];
                if (g > best) { best = g; bi = e; }
            }
            int pos = atomicAdd(&cnt[bi], 1);
            bucket[bi * NB + pos] = row;
        }
        __syncthreads();
    }
}

// ---------------- K2: We fp32 [E][K][N] -> bf16 transposed [E][N][K] ----------------
__global__ __launch_bounds__(256) void k_wet(const float* __restrict__ We,
                                             u16* __restrict__ WeT) {
    __shared__ float t[64 * 65];
    const int bw = blockIdx.x;
    const int e  = bw >> 8;
    const int n0 = ((bw >> 4) & 15) * 64;
    const int k0 = (bw & 15) * 64;
    const int tid = threadIdx.x;
    const float* src = We + (size_t)e * DK * DN;

    const int n4 = (tid & 15) * 4;
    const int kl = tid >> 4;
    #pragma unroll
    for (int r = 0; r < 4; ++r) {
        int k = r * 16 + kl;
        float4 v = *(const float4*)&src[(size_t)(k0 + k) * DN + n0 + n4];
        t[k * 65 + n4 + 0] = v.x;
        t[k * 65 + n4 + 1] = v.y;
        t[k * 65 + n4 + 2] = v.z;
        t[k * 65 + n4 + 3] = v.w;
    }
    __syncthreads();
    u16* dst = WeT + (size_t)e * DN * DK;
    #pragma unroll
    for (int r = 0; r < 2; ++r) {
        int idx = r * 256 + tid;
        int nl = idx >> 3;
        int k8 = idx & 7;
        u16 pk[8];
        #pragma unroll
        for (int i = 0; i < 8; ++i)
            pk[i] = f2bf(t[(k8 * 8 + i) * 65 + nl]);
        *(short8*)&dst[(size_t)(n0 + nl) * DK + k0 + k8 * 8] = *(const short8*)pk;
    }
}

// ---------------- K3: grouped GEMM, bf16 MFMA 16x16x32, 128x128 tile ----------------
__global__ __launch_bounds__(256) void k_moe(const u16* __restrict__ xb,
                                             const u16* __restrict__ WeT,
                                             const float* __restrict__ be,
                                             const int* __restrict__ bucket,
                                             const int* __restrict__ cnt,
                                             float* __restrict__ out) {
    const int slot = blockIdx.x >> 3;
    const int nt = blockIdx.x & 7;

    int e = -1, mt = 0, cntE = 0, acc_t = 0;
    #pragma unroll
    for (int ee = 0; ee < NE; ++ee) {
        int ce = cnt[ee];
        int nte = (ce + TM - 1) / TM;
        if (e < 0 && slot < acc_t + nte) { e = ee; mt = slot - acc_t; cntE = ce; }
        acc_t += nte;
    }
    if (e < 0) return;

    const int m0 = mt * TM;
    const int n0 = nt * TN;

    __shared__ u16 aLds[TM * BK];
    __shared__ u16 bLds[TN * BK];

    const int tid = threadIdx.x;
    const int lane = tid & 63;
    const int w = tid >> 6;
    const int wr = w >> 1, wc = w & 1;
    const int lr = lane & 15, q = lane >> 4;

    long aoff[4]; long boff[4]; int ldsb[4];
    #pragma unroll
    for (int r = 0; r < 4; ++r) {
        int c = r * 256 + tid;
        int row = c >> 3;
        int k8 = (c & 7) ^ (row & 7);
        int m_idx = m0 + row; if (m_idx >= cntE) m_idx = cntE - 1;
        long rid = bucket[e * NB + m_idx];
        aoff[r] = rid * DK + k8 * 8;
        boff[r] = (long)e * DN * DK + (long)(n0 + row) * DK + k8 * 8;
        ldsb[r] = (r * 256 + (tid & ~63)) * 8;
    }

    floatx4 acc[4][4];
    #pragma unroll
    for (int mi = 0; mi < 4; ++mi)
        #pragma unroll
        for (int ni = 0; ni < 4; ++ni)
            acc[mi][ni] = (floatx4)0.0f;

    for (int kk = 0; kk < DK; kk += BK) {
        #pragma unroll
        for (int r = 0; r < 4; ++r) {
            gld16(xb + aoff[r] + kk, &aLds[ldsb[r]]);
            gld16(WeT + boff[r] + kk, &bLds[ldsb[r]]);
        }
        __syncthreads();
        #pragma unroll
        for (int ks = 0; ks < 2; ++ks) {
            short8 af[4], bfr[4];
            const int slot_k = ((ks << 2) + q) ^ (lr & 7);
            #pragma unroll
            for (int mi = 0; mi < 4; ++mi) {
                int row = wr * 64 + mi * 16 + lr;
                af[mi] = *(const short8*)&aLds[row * BK + slot_k * 8];
                int nrow = wc * 64 + mi * 16 + lr;
                bfr[mi] = *(const short8*)&bLds[nrow * BK + slot_k * 8];
            }
            #pragma unroll
            for (int mi = 0; mi < 4; ++mi)
                #pragma unroll
                for (int ni = 0; ni < 4; ++ni)
                    acc[mi][ni] = __builtin_amdgcn_mfma_f32_16x16x32_bf16(
                        af[mi], bfr[ni], acc[mi][ni], 0, 0, 0);
        }
        __syncthreads();
    }

    float bias[4];
    #pragma unroll
    for (int ni = 0; ni < 4; ++ni)
        bias[ni] = be[e * DN + n0 + wc * 64 + ni * 16 + lr];

    #pragma unroll
    for (int mi = 0; mi < 4; ++mi) {
        #pragma unroll
        for (int rr = 0; rr < 4; ++rr) {
            int row_l = wr * 64 + mi * 16 + q * 4 + rr;
            int m_idx = m0 + row_l;
            if (m_idx < cntE) {
                long rid = bucket[e * NB + m_idx];
                float* orow = out + rid * DN + n0 + wc * 64 + lr;
                #pragma unroll
                for (int ni = 0; ni < 4; ++ni)
                    orow[ni * 16] = acc[mi][ni][rr] + bias[ni];
            }
        }
    }
}

extern "C" void kernel_launch(void* const* d_in, const int* in_sizes, int n_in,
                              void* d_out, int out_size, void* d_ws, size_t ws_size,
                              hipStream_t stream) {
    const float* x  = (const float*)d_in[0];
    const float* Wg = (const float*)d_in[1];
    const float* bg = (const float*)d_in[2];
    const float* We = (const float*)d_in[3];
    const float* be = (const float*)d_in[4];
    float* out = (float*)d_out;

    int* cnt     = (int*)d_ws;          // 16 ints
    int* fixcnt  = cnt + 16;            // 1 int
    int* fixlist = cnt + 32;            // up to 8192 ints
    int* bucket  = cnt + 8448;          // 16*8192 ints (ends < 1 MB)
    u16* xb  = (u16*)((char*)d_ws + (1u << 20));    // 16 MB @ 1MB
    u16* wet = (u16*)((char*)d_ws + (18u << 20));   // 32 MB @ 18MB

    hipMemsetAsync(cnt, 0, 20 * sizeof(int), stream);
    k_gate<<<512, 256, 0, stream>>>(x, Wg, bg, xb, cnt, bucket, fixcnt, fixlist);
    k_fix<<<256, 256, 0, stream>>>(x, Wg, bg, fixcnt, fixlist, cnt, bucket);
    k_wet<<<4096, 256, 0, stream>>>(We, wet);
    k_moe<<<MAX_TILES * 8, 256, 0, stream>>>(xb, wet, be, bucket, cnt, out);
}

// Round 6
// 216.694 us; speedup vs baseline: 1.4256x; 1.0738x over previous
//
#include <hip/hip_runtime.h>

typedef unsigned short u16;
typedef __attribute__((ext_vector_type(4))) unsigned short u16x4;
typedef __attribute__((ext_vector_type(8))) short short8;
typedef __attribute__((ext_vector_type(4))) float floatx4;

#define NB 8192        // rows
#define DK 1024        // D_IN
#define DN 1024        // D_OUT
#define NE 16          // experts
#define TM 128
#define TN 128
#define BK 128
#define MAX_TILES 80   // sum ceil(cnt_e/128) <= 64 + 16
#define GTHR 4e-3f     // split-bf16 gate error < 1e-4 worst-case; 40x margin

#define GATE_BLOCKS 512
#define WET_BLOCKS  4096

__device__ __forceinline__ u16 f2bf(float f) {
    union { float f; unsigned int u; } v; v.f = f;
    unsigned int u = v.u;
    return (u16)((u + 0x7fffu + ((u >> 16) & 1u)) >> 16);
}

__device__ __forceinline__ float bf2f(u16 h) {
    union { unsigned int u; float f; } v; v.u = ((unsigned int)h) << 16;
    return v.f;
}

__device__ __forceinline__ void gld16(const void* g, void* l) {
    __builtin_amdgcn_global_load_lds(
        (const __attribute__((address_space(1))) unsigned int*)g,
        (__attribute__((address_space(3))) unsigned int*)l, 16, 0, 0);
}

// ---------------- K1: fused [split-bf16 MFMA gate + x->bf16] | [We transpose] ----------------
// blocks 0..511: gate, 16 rows each. blocks 512..4607: We fp32 [E][K][N] -> bf16 [E][N][K].
__global__ __launch_bounds__(256) void k_prep(const float* __restrict__ x,
                                              const float* __restrict__ Wg,
                                              const float* __restrict__ bg,
                                              const float* __restrict__ We,
                                              u16* __restrict__ xb,
                                              u16* __restrict__ WeT,
                                              int* __restrict__ cnt,
                                              int* __restrict__ bucket,
                                              int* __restrict__ fixcnt,
                                              int* __restrict__ fixlist) {
    __shared__ union {
        struct {
            u16 xsh[4][16 * 64];
            u16 xsl[4][16 * 64];
            u16 wgh[4][16 * 64];
            u16 wgl[4][16 * 64];
            float gred[4][16 * 17];
        } g;                            // 36.4 KB
        float t[64 * 65];               // 16.6 KB
    } sh;

    const int tid = threadIdx.x;

    if (blockIdx.x < GATE_BLOCKS) {
        const int lane = tid & 63;
        const int w = tid >> 6;
        const int lr = lane & 15, q = lane >> 4;
        const int R0 = blockIdx.x * 16;
        const int kw = w * 256;         // wave k-base

        floatx4 acc = (floatx4)0.0f;

        for (int cc = 0; cc < 4; ++cc) {
            const int kc = kw + cc * 64;
            // stage x rows hi+lo bf16 swizzled + emit xb (hi) global copy
            #pragma unroll
            for (int i = 0; i < 2; ++i) {
                int c = i * 64 + lane;
                int r = c >> 3, s8 = c & 7;
                const float* gp = &x[(size_t)(R0 + r) * DK + kc + s8 * 8];
                float4 v0 = *(const float4*)gp;
                float4 v1 = *(const float4*)(gp + 4);
                float vv[8] = { v0.x, v0.y, v0.z, v0.w, v1.x, v1.y, v1.z, v1.w };
                u16 hi[8], lo[8];
                #pragma unroll
                for (int j = 0; j < 8; ++j) {
                    hi[j] = f2bf(vv[j]);
                    lo[j] = f2bf(vv[j] - bf2f(hi[j]));
                }
                int a = r * 64 + ((s8 ^ (r & 7)) * 8);
                *(short8*)&sh.g.xsh[w][a] = *(const short8*)hi;
                *(short8*)&sh.g.xsl[w][a] = *(const short8*)lo;
                *(short8*)&xb[(size_t)(R0 + r) * DK + kc + s8 * 8] = *(const short8*)hi;
            }
            // stage Wg chunk transposed hi+lo
            #pragma unroll
            for (int i = 0; i < 4; ++i) {
                int f = i * 64 + lane;
                int k = f >> 2;
                int e4 = (f & 3) * 4;
                float4 v = *(const float4*)&Wg[(size_t)(kc + k) * NE + e4];
                int s = k >> 3, j = k & 7;
                float vv[4] = { v.x, v.y, v.z, v.w };
                #pragma unroll
                for (int t2 = 0; t2 < 4; ++t2) {
                    int er = e4 + t2;
                    u16 hi = f2bf(vv[t2]);
                    u16 lo = f2bf(vv[t2] - bf2f(hi));
                    int a = er * 64 + ((s ^ (er & 7)) * 8 + j);
                    sh.g.wgh[w][a] = hi;
                    sh.g.wgl[w][a] = lo;
                }
            }
            __syncthreads();
            #pragma unroll
            for (int kwin = 0; kwin < 2; ++kwin) {
                int sg = kwin * 4 + q;
                int ab = lr * 64 + ((sg ^ (lr & 7)) * 8);
                short8 bh = *(const short8*)&sh.g.wgh[w][ab];
                short8 bl = *(const short8*)&sh.g.wgl[w][ab];
                short8 ah = *(const short8*)&sh.g.xsh[w][ab];
                short8 al = *(const short8*)&sh.g.xsl[w][ab];
                acc = __builtin_amdgcn_mfma_f32_16x16x32_bf16(ah, bh, acc, 0, 0, 0);
                acc = __builtin_amdgcn_mfma_f32_16x16x32_bf16(ah, bl, acc, 0, 0, 0);
                acc = __builtin_amdgcn_mfma_f32_16x16x32_bf16(al, bh, acc, 0, 0, 0);
            }
            __syncthreads();
        }

        #pragma unroll
        for (int rr = 0; rr < 4; ++rr)
            sh.g.gred[w][(q * 4 + rr) * 17 + lr] = acc[rr];
        __syncthreads();

        if (tid < 16) {
            int row = R0 + tid;
            float g[16];
            #pragma unroll
            for (int e = 0; e < 16; ++e)
                g[e] = sh.g.gred[0][tid * 17 + e] + sh.g.gred[1][tid * 17 + e]
                     + sh.g.gred[2][tid * 17 + e] + sh.g.gred[3][tid * 17 + e] + bg[e];
            float best = g[0], second = -1e30f; int bi = 0;
            #pragma unroll
            for (int e = 1; e < 16; ++e) {
                if (g[e] > best) { second = best; best = g[e]; bi = e; }
                else if (g[e] > second) second = g[e];
            }
            if (best - second >= GTHR) {
                int pos = atomicAdd(&cnt[bi], 1);
                bucket[bi * NB + pos] = row;
            } else {
                int f = atomicAdd(fixcnt, 1);
                fixlist[f] = row;
            }
        }
    } else {
        // ---- transpose branch ----
        const int bw = blockIdx.x - GATE_BLOCKS;
        const int e  = bw >> 8;
        const int n0 = ((bw >> 4) & 15) * 64;
        const int k0 = (bw & 15) * 64;
        const float* src = We + (size_t)e * DK * DN;
        float* t = sh.t;

        const int n4 = (tid & 15) * 4;
        const int kl = tid >> 4;
        #pragma unroll
        for (int r = 0; r < 4; ++r) {
            int k = r * 16 + kl;
            float4 v = *(const float4*)&src[(size_t)(k0 + k) * DN + n0 + n4];
            t[k * 65 + n4 + 0] = v.x;
            t[k * 65 + n4 + 1] = v.y;
            t[k * 65 + n4 + 2] = v.z;
            t[k * 65 + n4 + 3] = v.w;
        }
        __syncthreads();
        u16* dst = WeT + (size_t)e * DN * DK;
        #pragma unroll
        for (int r = 0; r < 2; ++r) {
            int idx = r * 256 + tid;
            int nl = idx >> 3;
            int k8 = idx & 7;
            u16 pk[8];
            #pragma unroll
            for (int i = 0; i < 8; ++i)
                pk[i] = f2bf(t[(k8 * 8 + i) * 65 + nl]);
            *(short8*)&dst[(size_t)(n0 + nl) * DK + k0 + k8 * 8] = *(const short8*)pk;
        }
    }
}

// ---------------- K1b: fp64 exact re-gate of ambiguous rows (block per row) ----------------
__global__ __launch_bounds__(256) void k_fix(const float* __restrict__ x,
                                             const float* __restrict__ Wg,
                                             const float* __restrict__ bg,
                                             const int* __restrict__ fixcnt,
                                             const int* __restrict__ fixlist,
                                             int* __restrict__ cnt,
                                             int* __restrict__ bucket) {
    __shared__ double lred[4][16];
    const int tid = threadIdx.x;
    const int lane = tid & 63;
    const int w = tid >> 6;
    const int n = *fixcnt;
    for (int it = blockIdx.x; it < n; it += 256) {
        const int row = fixlist[it];
        float4 xv = *(const float4*)&x[(size_t)row * DK + tid * 4];
        const float* xf = (const float*)&xv;
        double acc[16];
        #pragma unroll
        for (int e = 0; e < 16; ++e) acc[e] = 0.0;
        #pragma unroll
        for (int j = 0; j < 4; ++j) {
            int k = tid * 4 + j;
            double xd = (double)xf[j];
            const float4* wr = (const float4*)&Wg[(size_t)k * NE];
            float4 w0 = wr[0], w1 = wr[1], w2 = wr[2], w3 = wr[3];
            acc[0]  += xd * (double)w0.x;  acc[1]  += xd * (double)w0.y;
            acc[2]  += xd * (double)w0.z;  acc[3]  += xd * (double)w0.w;
            acc[4]  += xd * (double)w1.x;  acc[5]  += xd * (double)w1.y;
            acc[6]  += xd * (double)w1.z;  acc[7]  += xd * (double)w1.w;
            acc[8]  += xd * (double)w2.x;  acc[9]  += xd * (double)w2.y;
            acc[10] += xd * (double)w2.z;  acc[11] += xd * (double)w2.w;
            acc[12] += xd * (double)w3.x;  acc[13] += xd * (double)w3.y;
            acc[14] += xd * (double)w3.z;  acc[15] += xd * (double)w3.w;
        }
        #pragma unroll
        for (int e = 0; e < 16; ++e) {
            double v = acc[e];
            #pragma unroll
            for (int off = 1; off < 64; off <<= 1)
                v += __shfl_xor(v, off);
            acc[e] = v;
        }
        if (lane == 0) {
            #pragma unroll
            for (int e = 0; e < 16; ++e) lred[w][e] = acc[e];
        }
        __syncthreads();
        if (tid == 0) {
            double best = -1e300; int bi = 0;
            #pragma unroll
            for (int e = 0; e < 16; ++e) {
                double g = lred[0][e] + lred[1][e] + lred[2][e] + lred[3][e]
                         + (double)bg[e];
                if (g > best) { best = g; bi = e; }
            }
            int pos = atomicAdd(&cnt[bi], 1);
            bucket[bi * NB + pos] = row;
        }
        __syncthreads();
    }
}

// ---------------- K3: grouped GEMM, bf16 MFMA 16x16x32, 128x128 tile, BK=128 ----------------
__global__ __launch_bounds__(256) void k_moe(const u16* __restrict__ xb,
                                             const u16* __restrict__ WeT,
                                             const float* __restrict__ be,
                                             const int* __restrict__ bucket,
                                             const int* __restrict__ cnt,
                                             float* __restrict__ out) {
    const int slot = blockIdx.x >> 3;
    const int nt = blockIdx.x & 7;

    int e = -1, mt = 0, cntE = 0, acc_t = 0;
    #pragma unroll
    for (int ee = 0; ee < NE; ++ee) {
        int ce = cnt[ee];
        int nte = (ce + TM - 1) / TM;
        if (e < 0 && slot < acc_t + nte) { e = ee; mt = slot - acc_t; cntE = ce; }
        acc_t += nte;
    }
    if (e < 0) return;

    const int m0 = mt * TM;
    const int n0 = nt * TN;

    __shared__ u16 aLds[TM * BK];   // 32 KB
    __shared__ u16 bLds[TN * BK];   // 32 KB

    const int tid = threadIdx.x;
    const int lane = tid & 63;
    const int w = tid >> 6;
    const int wr = w >> 1, wc = w & 1;
    const int lr = lane & 15, q = lane >> 4;

    // staging: chunk c (0..2047) -> row = c>>4, stored slot = c&15, global k16 = slot ^ (row&15)
    long aoff[8]; long boff[8]; int ldsb[8];
    #pragma unroll
    for (int r = 0; r < 8; ++r) {
        int c = r * 256 + tid;
        int row = c >> 4;
        int k16 = (c & 15) ^ (row & 15);
        int m_idx = m0 + row; if (m_idx >= cntE) m_idx = cntE - 1;
        long rid = bucket[e * NB + m_idx];
        aoff[r] = rid * DK + k16 * 8;
        boff[r] = (long)e * DN * DK + (long)(n0 + row) * DK + k16 * 8;
        ldsb[r] = (r * 256 + (tid & ~63)) * 8;   // u16 elems; wave-contiguous 1 KB
    }

    floatx4 acc[4][4];
    #pragma unroll
    for (int mi = 0; mi < 4; ++mi)
        #pragma unroll
        for (int ni = 0; ni < 4; ++ni)
            acc[mi][ni] = (floatx4)0.0f;

    for (int kk = 0; kk < DK; kk += BK) {
        #pragma unroll
        for (int r = 0; r < 8; ++r)
            gld16(xb + aoff[r] + kk, &aLds[ldsb[r]]);
        #pragma unroll
        for (int r = 0; r < 8; ++r)
            gld16(WeT + boff[r] + kk, &bLds[ldsb[r]]);
        __syncthreads();
        #pragma unroll
        for (int ks = 0; ks < 4; ++ks) {
            const int kt = ks * 4 + q;      // k16-slot for this MFMA window
            short8 af[4], bfr[4];
            #pragma unroll
            for (int mi = 0; mi < 4; ++mi) {
                int row = wr * 64 + mi * 16 + lr;
                af[mi] = *(const short8*)&aLds[row * BK + ((kt ^ (row & 15)) * 8)];
                int nrow = wc * 64 + mi * 16 + lr;
                bfr[mi] = *(const short8*)&bLds[nrow * BK + ((kt ^ (nrow & 15)) * 8)];
            }
            #pragma unroll
            for (int mi = 0; mi < 4; ++mi)
                #pragma unroll
                for (int ni = 0; ni < 4; ++ni)
                    acc[mi][ni] = __builtin_amdgcn_mfma_f32_16x16x32_bf16(
                        af[mi], bfr[ni], acc[mi][ni], 0, 0, 0);
        }
        __syncthreads();
    }

    float bias[4];
    #pragma unroll
    for (int ni = 0; ni < 4; ++ni)
        bias[ni] = be[e * DN + n0 + wc * 64 + ni * 16 + lr];

    #pragma unroll
    for (int mi = 0; mi < 4; ++mi) {
        #pragma unroll
        for (int rr = 0; rr < 4; ++rr) {
            int row_l = wr * 64 + mi * 16 + q * 4 + rr;
            int m_idx = m0 + row_l;
            if (m_idx < cntE) {
                long rid = bucket[e * NB + m_idx];
                float* orow = out + rid * DN + n0 + wc * 64 + lr;
                #pragma unroll
                for (int ni = 0; ni < 4; ++ni)
                    orow[ni * 16] = acc[mi][ni][rr] + bias[ni];
            }
        }
    }
}

extern "C" void kernel_launch(void* const* d_in, const int* in_sizes, int n_in,
                              void* d_out, int out_size, void* d_ws, size_t ws_size,
                              hipStream_t stream) {
    const float* x  = (const float*)d_in[0];
    const float* Wg = (const float*)d_in[1];
    const float* bg = (const float*)d_in[2];
    const float* We = (const float*)d_in[3];
    const float* be = (const float*)d_in[4];
    float* out = (float*)d_out;

    int* cnt     = (int*)d_ws;          // 16 ints
    int* fixcnt  = cnt + 16;            // 1 int
    int* fixlist = cnt + 32;            // up to 8192 ints
    int* bucket  = cnt + 8448;          // 16*8192 ints (ends < 1 MB)
    u16* xb  = (u16*)((char*)d_ws + (1u << 20));    // 16 MB @ 1MB
    u16* wet = (u16*)((char*)d_ws + (18u << 20));   // 32 MB @ 18MB

    hipMemsetAsync(cnt, 0, 20 * sizeof(int), stream);
    k_prep<<<GATE_BLOCKS + WET_BLOCKS, 256, 0, stream>>>(x, Wg, bg, We, xb, wet,
                                                         cnt, bucket, fixcnt, fixlist);
    k_fix<<<256, 256, 0, stream>>>(x, Wg, bg, fixcnt, fixlist, cnt, bucket);
    k_moe<<<MAX_TILES * 8, 256, 0, stream>>>(xb, wet, be, bucket, cnt, out);
}